// Round 2
// baseline (1741.224 us; speedup 1.0000x reference)
//
#include <hip/hip_runtime.h>
#include <stdint.h>

#define NROWS 4096   // S*B
#define HDIM  512
#define GDIM  2048   // 4*H
#define WWIN  32

typedef __attribute__((ext_vector_type(8))) short short8;
typedef __attribute__((ext_vector_type(4))) float f32x4;

__device__ __forceinline__ unsigned short f2bf(float x){
  union { float f; unsigned int u; } v; v.f = x;
  unsigned int u = v.u + 0x7fffu + ((v.u >> 16) & 1u);
  return (unsigned short)(u >> 16);
}
__device__ __forceinline__ float bf2f(unsigned short u){
  union { unsigned int u; float f; } v; v.u = ((unsigned int)u) << 16; return v.f;
}

__device__ __forceinline__ void gld16(const void* g, void* l){
  __builtin_amdgcn_global_load_lds(
      (const __attribute__((address_space(1))) unsigned int*)g,
      (__attribute__((address_space(3))) unsigned int*)l, 16, 0, 0);
}

__device__ __forceinline__ float sigm(float x){ return 1.f/(1.f + __expf(-x)); }
__device__ __forceinline__ float tanh_f(float x){ return 1.f - 2.f/(1.f + __expf(2.f*x)); }

// ---- device-scope grid barrier (persistent kernel; all blocks co-resident) ---
// release-fence (wbl2: push this block's h-writes to memory-visible point) ->
// relaxed agent fetch_add arrive -> last block bumps generation (release) ->
// others spin on RELAXED agent load (sc1, bypasses L2: no deadlock, no inv
// per poll) -> acquire-fence (inv: drop stale h lines) on exit.
__device__ __forceinline__ void grid_sync(unsigned* bar, unsigned target){
  __syncthreads();   // drains each wave's vmcnt/lgkmcnt before barrier
  if (threadIdx.x == 0){
    __builtin_amdgcn_fence(__ATOMIC_RELEASE, "agent");
    unsigned arrived = __hip_atomic_fetch_add(&bar[0], 1u, __ATOMIC_RELAXED,
                                              __HIP_MEMORY_SCOPE_AGENT);
    if (arrived == gridDim.x - 1){
      __hip_atomic_store(&bar[0], 0u, __ATOMIC_RELAXED, __HIP_MEMORY_SCOPE_AGENT);
      __hip_atomic_store(&bar[1], target, __ATOMIC_RELEASE, __HIP_MEMORY_SCOPE_AGENT);
    } else {
      while (__hip_atomic_load(&bar[1], __ATOMIC_RELAXED, __HIP_MEMORY_SCOPE_AGENT) < target)
        __builtin_amdgcn_s_sleep(8);
    }
    __builtin_amdgcn_fence(__ATOMIC_ACQUIRE, "agent");
  }
  __syncthreads();
}

// ------------- double-buffered 128x128 GEMM core (bf16, BT weight layout) -----
// (p0_gemm only)
__device__ __forceinline__ void gemm_tile_db(
    const char* A0, const char* A1, const char* Bsrc,
    int ldbB, int nk, int r0, int c0,
    char* smem, int wr, int wc, int lane, f32x4 acc[4][4])
{
  const int tid = threadIdx.x;
  const int oo0 = tid * 16;
  const int srow = oo0 >> 7;
  const int scb  = oo0 & 127;
  const size_t aOff = (size_t)(r0 + srow) * 1024 + scb;
  const size_t bOff = (size_t)(c0 + srow) * (size_t)ldbB + scb;

  auto STAGE = [&](int kk, int buf){
    const char* Ap = (kk < 8) ? A0 : A1;
    const size_t kbA = (size_t)(kk & 7) * 128;
    const size_t kbB = (size_t)kk * 128;
    char* AsB = smem + buf * 16384;
    char* BsB = smem + 32768 + buf * 16384;
    #pragma unroll
    for (int i = 0; i < 4; ++i){
      const size_t rstep = (size_t)i * 32;
      gld16(Ap   + aOff + rstep * 1024          + kbA, AsB + i*4096 + oo0);
      gld16(Bsrc + bOff + rstep * (size_t)ldbB  + kbB, BsB + i*4096 + oo0);
    }
  };

  STAGE(0, 0);
  __syncthreads();

  const int lr = lane & 15;
  const int lk = (lane >> 4) * 8;

  for (int kk = 0; kk < nk; ++kk){
    const int cur = kk & 1;
    if (kk + 1 < nk) STAGE(kk + 1, cur ^ 1);

    const unsigned short* As = (const unsigned short*)(smem + cur*16384);
    const unsigned short* Bs = (const unsigned short*)(smem + 32768 + cur*16384);
    short8 a[2][4], b[2][4];
    #pragma unroll
    for (int h = 0; h < 2; ++h){
      const int k32 = h * 32;
      #pragma unroll
      for (int m = 0; m < 4; ++m)
        a[h][m] = *(const short8*)(As + (64*wr + 16*m + lr)*64 + k32 + lk);
      #pragma unroll
      for (int n = 0; n < 4; ++n)
        b[h][n] = *(const short8*)(Bs + (64*wc + 16*n + lr)*64 + k32 + lk);
    }
    __builtin_amdgcn_s_setprio(1);
    #pragma unroll
    for (int h = 0; h < 2; ++h)
      #pragma unroll
      for (int m = 0; m < 4; ++m)
        #pragma unroll
        for (int n = 0; n < 4; ++n)
          acc[m][n] = __builtin_amdgcn_mfma_f32_16x16x32_bf16(a[h][m], b[h][n], acc[m][n], 0, 0, 0);
    __builtin_amdgcn_s_setprio(0);

    __syncthreads();
  }
}

// ---------------- prep: reorder weights gate-interleaved, cast bf16 -----------
__global__ void __launch_bounds__(256) prep_weights(
    const float* wih0, const float* whh0, const float* bih0, const float* bhh0,
    const float* wih1, const float* whh1, const float* bih1, const float* bhh1,
    unsigned short* BrIh0, unsigned short* Br0, unsigned short* Br1,
    float* bias0r, float* br1)
{
  const int j = blockIdx.x;
  const int g = j & 3, hd = j >> 2;
  const int r = g*512 + hd;
  for (int k = threadIdx.x; k < 512; k += 256){
    BrIh0[(size_t)j*512 + k]      = f2bf(wih0[(size_t)r*512 + k]);
    Br0  [(size_t)j*512 + k]      = f2bf(whh0[(size_t)r*512 + k]);
    Br1  [(size_t)j*1024 + k]     = f2bf(wih1[(size_t)r*512 + k]);
    Br1  [(size_t)j*1024 + 512+k] = f2bf(whh1[(size_t)r*512 + k]);
  }
  if (threadIdx.x == 0){
    bias0r[j] = bih0[r] + bhh0[r];
    br1[j]    = bih1[r] + bhh1[r];
  }
}

// ---------------- embedding gather (fp32 -> bf16) -----------------------------
__global__ void __launch_bounds__(256) gather_embed(const int* enc, const float* tbl,
                                                    unsigned short* E)
{
  const int n = blockIdx.x;
  const int idx = enc[n];
  const float* src = tbl + (size_t)idx * 512;
  unsigned short* dst = E + (size_t)n * 512;
  for (int e = threadIdx.x; e < 512; e += 256) dst[e] = f2bf(src[e]);
}

// ---------------- P0 = E @ BrIh0^T + bias0r (bf16 out, interleaved cols) ------
__global__ void __launch_bounds__(256) p0_gemm(const unsigned short* E,
                                               const unsigned short* BrIh0,
                                               const float* bias0r,
                                               unsigned short* P0)
{
  __shared__ __align__(16) char smem[65536];
  const int tid  = threadIdx.x;
  const int lane = tid & 63, wid = tid >> 6;
  const int wr = wid >> 1, wc = wid & 1;
  const int bid = blockIdx.x;
  const int r0 = (bid >> 4) * 128, c0 = (bid & 15) * 128;
  f32x4 acc[4][4] = {};
  gemm_tile_db((const char*)E, nullptr, (const char*)BrIh0, 1024, 8,
               r0, c0, smem, wr, wc, lane, acc);
  #pragma unroll
  for (int m = 0; m < 4; ++m){
    const int rowb = r0 + 64*wr + 16*m + ((lane >> 4) << 2);
    #pragma unroll
    for (int n = 0; n < 4; ++n){
      const int colb = c0 + 64*wc + 16*n + (lane & 15);
      const float bs = bias0r[colb];
      #pragma unroll
      for (int r = 0; r < 4; ++r)
        P0[(size_t)(rowb + r)*GDIM + colb] = f2bf(acc[m][n][r] + bs);
    }
  }
}

// ============== persistent fused kernel: all 33 steps, both layers ============
// 256 blocks x 512 thr, 1 block/CU (128KB LDS). Block identity (layer, 256x256
// tile) fixed across tau => its c-state slice (256 rows x 16 hd per thread
// partition = 32 f32/thread) lives in REGISTERS for the whole sequence.
// Per tau: GEMM (R1's verified 4-slot-ring counted-vmcnt pipeline) + pointwise,
// then device-scope grid barrier. h0/h1 parity-double-buffered in global.
__global__ void __launch_bounds__(512, 2) persist_kernel(
    unsigned short* h0, unsigned short* h1,
    const unsigned short* Br0, const unsigned short* Br1,
    const unsigned short* P0, const float* br1, float* out, unsigned* bar)
{
  extern __shared__ __align__(16) char smem[];

  // XCD-balanced bijective mapping: XCD x gets 16 L0 + 16 L1 tiles.
  const int x = blockIdx.x & 7, kq = blockIdx.x >> 3;
  const int wk = ((kq & 1) << 7) + x * 16 + (kq >> 1);
  const bool L1 = (wk >= 128);
  const int lb = L1 ? (wk - 128) : wk;
  const int r0  = (lb >> 3) * 256;
  const int c0v = (lb & 7) * 256;

  const int tid  = threadIdx.x;
  const int lane = tid & 63, wid = tid >> 6;
  const int wm = wid >> 2, wn = wid & 3;
  const int lr = lane & 15, sl = lane >> 4;

  const int srow  = tid >> 2;
  const int sbyte = ((tid & 3) ^ ((tid >> 3) & 3)) << 4;   // inverse-swz source
  const int ph    = (sl ^ ((lr >> 1) & 3)) << 4;           // swz ds_read slot
  const int laneA = (wm*128 + lr) * 64 + ph;
  const int laneB = (wn*64  + lr) * 64 + ph;

  const char* Bp  = (const char*)(L1 ? Br1 : Br0);
  const int  ldbB = L1 ? 2048 : 1024;
  const int  nkt  = L1 ? 32 : 16;

  float creg[4][8];
  #pragma unroll
  for (int p = 0; p < 4; ++p)
    #pragma unroll
    for (int i = 0; i < 8; ++i) creg[p][i] = 0.f;

  for (int tau = 0; tau <= 33; ++tau){
    const bool active = L1 ? (tau >= 1) : (tau <= 32);
    if (active){
      const int t  = L1 ? (tau - 1) : tau;
      const int pr = (tau + 1) & 1, pw = tau & 1;
      const unsigned short* hA0 = h0 + (size_t)pr * (NROWS*HDIM);
      const unsigned short* hA1 = h1 + (size_t)pr * (NROWS*HDIM);

      auto STAGE_A = [&](int kt2, int c){
        const char* Ap; int kB;
        if (!L1 || kt2 < 16){ Ap = (const char*)hA0; kB = kt2 * 64; }
        else                { Ap = (const char*)hA1; kB = (kt2 - 16) * 64; }
        gld16(Ap + (size_t)(r0 + c*128 + srow) * 1024 + kB + sbyte,
              smem + (size_t)(kt2 & 3) * 32768 + c*8192 + tid*16);
      };
      auto STAGE_B = [&](int kt2, int c){
        gld16(Bp + (size_t)(c0v + c*128 + srow) * (size_t)ldbB + kt2*64 + sbyte,
              smem + (size_t)(kt2 & 3) * 32768 + 16384 + c*8192 + tid*16);
      };

      f32x4 acc[8][4] = {};

      STAGE_A(0,0); STAGE_A(0,1); STAGE_B(0,0); STAGE_B(0,1);
      STAGE_A(1,0); STAGE_A(1,1); STAGE_B(1,0); STAGE_B(1,1);
      asm volatile("s_waitcnt vmcnt(4)" ::: "memory");
      __builtin_amdgcn_s_barrier();

      for (int kt = 0; kt < nkt; ++kt){
        const char* bufp = smem + (size_t)(kt & 3) * 32768;
        const bool st = (kt + 2) < nkt;
        short8 a0[4], a1[4], b[4];

        // ---- phase 0 ----
        #pragma unroll
        for (int m = 0; m < 4; ++m) a0[m] = *(const short8*)(bufp + laneA + m*1024);
        #pragma unroll
        for (int n = 0; n < 4; ++n) b[n]  = *(const short8*)(bufp + 16384 + laneB + n*1024);
        if (st){ STAGE_A(kt+2, 0); STAGE_A(kt+2, 1); }
        __builtin_amdgcn_s_barrier();
        asm volatile("s_waitcnt lgkmcnt(0)" ::: "memory");
        __builtin_amdgcn_sched_barrier(0);
        __builtin_amdgcn_s_setprio(1);
        #pragma unroll
        for (int m = 0; m < 4; ++m)
          #pragma unroll
          for (int n = 0; n < 4; ++n)
            acc[m][n] = __builtin_amdgcn_mfma_f32_16x16x32_bf16(a0[m], b[n], acc[m][n], 0, 0, 0);
        __builtin_amdgcn_s_setprio(0);
        __builtin_amdgcn_s_barrier();

        // ---- phase 1 ----
        #pragma unroll
        for (int m = 0; m < 4; ++m) a1[m] = *(const short8*)(bufp + laneA + (4+m)*1024);
        if (st){
          STAGE_B(kt+2, 0); STAGE_B(kt+2, 1);
          asm volatile("s_waitcnt vmcnt(4)" ::: "memory");
        } else {
          asm volatile("s_waitcnt vmcnt(0)" ::: "memory");
        }
        __builtin_amdgcn_s_barrier();
        asm volatile("s_waitcnt lgkmcnt(0)" ::: "memory");
        __builtin_amdgcn_sched_barrier(0);
        __builtin_amdgcn_s_setprio(1);
        #pragma unroll
        for (int m = 0; m < 4; ++m)
          #pragma unroll
          for (int n = 0; n < 4; ++n)
            acc[4+m][n] = __builtin_amdgcn_mfma_f32_16x16x32_bf16(a1[m], b[n], acc[4+m][n], 0, 0, 0);
        __builtin_amdgcn_s_setprio(0);
        __builtin_amdgcn_s_barrier();
      }

      // ---- epilogue: LSTM pointwise, c in registers ----
      float* GLDS = (float*)smem;
      const int GST = 68;
      unsigned short* hw = (L1 ? h1 : h0) + (size_t)pw * (NROWS*HDIM);
      const bool finalStep = (L1 && t == 32);

      #pragma unroll
      for (int pass = 0; pass < 4; ++pass){
        __syncthreads();
        if (wn == pass){
          #pragma unroll
          for (int m = 0; m < 8; ++m){
            const int rowb = wm*128 + m*16 + (sl << 2);
            #pragma unroll
            for (int n = 0; n < 4; ++n){
              const int colb = n*16 + lr;
              const f32x4 v = acc[m][n];
              #pragma unroll
              for (int r = 0; r < 4; ++r)
                GLDS[(rowb + r)*GST + colb] = v[r];
            }
          }
        }
        __syncthreads();
        #pragma unroll
        for (int it = 0; it < 8; ++it){
          const int cid = it*512 + tid;          // 4096 cells: 256 rows x 16 hd
          const int row = cid >> 4;
          const int l   = cid & 15;
          const int rowg = r0 + row;
          const int hd   = (c0v >> 2) + pass*16 + l;
          float4 gv = *(const float4*)&GLDS[row*GST + 4*l];
          float gi = gv.x, gf = gv.y, gg = gv.z, go = gv.w;
          const int s  = rowg >> 3;
          const int bb = rowg & 7;
          const int pos = s - WWIN + t;
          if (!L1){
            const int p0r = (pos < 0 ? 0 : pos)*8 + bb;
            const ushort4 pv = *(const ushort4*)&P0[(size_t)p0r*GDIM + 4*hd];
            gi += bf2f(pv.x); gf += bf2f(pv.y); gg += bf2f(pv.z); go += bf2f(pv.w);
          } else {
            float4 bv = *(const float4*)&br1[4*hd];
            gi += bv.x; gf += bv.y; gg += bv.z; go += bv.w;
          }
          float cp = creg[pass][it];
          float i_ = sigm(gi), f_ = sigm(gf), g_ = tanh_f(gg), o_ = sigm(go);
          float cn = f_*cp + i_*g_;
          float hn = o_*tanh_f(cn);
          if (pos < 0){ cn = 0.f; hn = 0.f; }
          creg[pass][it] = cn;
          const size_t sidx = (size_t)rowg*HDIM + hd;
          if (finalStep) out[sidx] = hn;
          else           hw[sidx]  = f2bf(hn);
        }
      }
    }
    grid_sync(bar, (unsigned)(tau + 1));
  }
}

// ---------------- fallback per-step kernel (non-cooperative path) -------------
__global__ void __launch_bounds__(512, 2) step_kernel(
    unsigned short* h0, unsigned short* h1, float* c0b, float* c1b,
    const unsigned short* Br0, const unsigned short* Br1,
    const unsigned short* P0, const float* br1, float* out, int tau, int bidOff)
{
  extern __shared__ __align__(16) char smem[];

  const int x = blockIdx.x & 7, kq = blockIdx.x >> 3;
  int wk;
  if (gridDim.x == 256) wk = ((kq & 1) << 7) + x * 16 + (kq >> 1);
  else                  wk = x * 16 + kq;
  wk += bidOff;

  const bool L1 = (wk >= 128);
  const int t  = L1 ? (tau - 1) : tau;
  const int pr = (tau + 1) & 1, pw = tau & 1;
  const int lb = L1 ? (wk - 128) : wk;
  const int r0  = (lb >> 3) * 256;
  const int c0v = (lb & 7) * 256;

  const int tid  = threadIdx.x;
  const int lane = tid & 63;
  const int wid  = tid >> 6;
  const int wm = wid >> 2, wn = wid & 3;
  const int lr = lane & 15, sl = lane >> 4;

  const unsigned short* hA0 = h0 + (size_t)pr * (NROWS*HDIM);
  const unsigned short* hA1 = h1 + (size_t)pr * (NROWS*HDIM);
  const char* Bp  = (const char*)(L1 ? Br1 : Br0);
  const int  ldbB = L1 ? 2048 : 1024;
  const int  nkt  = L1 ? 32 : 16;

  const int srow  = tid >> 2;
  const int sbyte = ((tid & 3) ^ ((tid >> 3) & 3)) << 4;
  const int ph    = (sl ^ ((lr >> 1) & 3)) << 4;
  const int laneA = (wm*128 + lr) * 64 + ph;
  const int laneB = (wn*64  + lr) * 64 + ph;

  auto STAGE_A = [&](int kt2, int c){
    const char* Ap; int kB;
    if (!L1 || kt2 < 16){ Ap = (const char*)hA0; kB = kt2 * 64; }
    else                { Ap = (const char*)hA1; kB = (kt2 - 16) * 64; }
    gld16(Ap + (size_t)(r0 + c*128 + srow) * 1024 + kB + sbyte,
          smem + (size_t)(kt2 & 3) * 32768 + c*8192 + tid*16);
  };
  auto STAGE_B = [&](int kt2, int c){
    gld16(Bp + (size_t)(c0v + c*128 + srow) * (size_t)ldbB + kt2*64 + sbyte,
          smem + (size_t)(kt2 & 3) * 32768 + 16384 + c*8192 + tid*16);
  };

  f32x4 acc[8][4] = {};

  STAGE_A(0,0); STAGE_A(0,1); STAGE_B(0,0); STAGE_B(0,1);
  STAGE_A(1,0); STAGE_A(1,1); STAGE_B(1,0); STAGE_B(1,1);
  asm volatile("s_waitcnt vmcnt(4)" ::: "memory");
  __builtin_amdgcn_s_barrier();

  for (int kt = 0; kt < nkt; ++kt){
    const char* bufp = smem + (size_t)(kt & 3) * 32768;
    const bool st = (kt + 2) < nkt;
    short8 a0[4], a1[4], b[4];

    #pragma unroll
    for (int m = 0; m < 4; ++m) a0[m] = *(const short8*)(bufp + laneA + m*1024);
    #pragma unroll
    for (int n = 0; n < 4; ++n) b[n]  = *(const short8*)(bufp + 16384 + laneB + n*1024);
    if (st){ STAGE_A(kt+2, 0); STAGE_A(kt+2, 1); }
    __builtin_amdgcn_s_barrier();
    asm volatile("s_waitcnt lgkmcnt(0)" ::: "memory");
    __builtin_amdgcn_sched_barrier(0);
    __builtin_amdgcn_s_setprio(1);
    #pragma unroll
    for (int m = 0; m < 4; ++m)
      #pragma unroll
      for (int n = 0; n < 4; ++n)
        acc[m][n] = __builtin_amdgcn_mfma_f32_16x16x32_bf16(a0[m], b[n], acc[m][n], 0, 0, 0);
    __builtin_amdgcn_s_setprio(0);
    __builtin_amdgcn_s_barrier();

    #pragma unroll
    for (int m = 0; m < 4; ++m) a1[m] = *(const short8*)(bufp + laneA + (4+m)*1024);
    if (st){
      STAGE_B(kt+2, 0); STAGE_B(kt+2, 1);
      asm volatile("s_waitcnt vmcnt(4)" ::: "memory");
    } else {
      asm volatile("s_waitcnt vmcnt(0)" ::: "memory");
    }
    __builtin_amdgcn_s_barrier();
    asm volatile("s_waitcnt lgkmcnt(0)" ::: "memory");
    __builtin_amdgcn_sched_barrier(0);
    __builtin_amdgcn_s_setprio(1);
    #pragma unroll
    for (int m = 0; m < 4; ++m)
      #pragma unroll
      for (int n = 0; n < 4; ++n)
        acc[4+m][n] = __builtin_amdgcn_mfma_f32_16x16x32_bf16(a1[m], b[n], acc[4+m][n], 0, 0, 0);
    __builtin_amdgcn_s_setprio(0);
    __builtin_amdgcn_s_barrier();
  }

  float* GLDS = (float*)smem;
  const int GST = 68;
  float* cbuf = L1 ? c1b : c0b;
  unsigned short* hw = (L1 ? h1 : h0) + (size_t)pw * (NROWS*HDIM);
  const bool finalStep = (L1 && t == 32);

  for (int pass = 0; pass < 4; ++pass){
    __syncthreads();
    if (wn == pass){
      #pragma unroll
      for (int m = 0; m < 8; ++m){
        const int rowb = wm*128 + m*16 + (sl << 2);
        #pragma unroll
        for (int n = 0; n < 4; ++n){
          const int colb = n*16 + lr;
          const f32x4 v = acc[m][n];
          #pragma unroll
          for (int r = 0; r < 4; ++r)
            GLDS[(rowb + r)*GST + colb] = v[r];
        }
      }
    }
    __syncthreads();
    #pragma unroll
    for (int it = 0; it < 8; ++it){
      const int cid = it*512 + tid;
      const int row = cid >> 4;
      const int l   = cid & 15;
      const int rowg = r0 + row;
      const int hd   = (c0v >> 2) + pass*16 + l;
      float4 gv = *(const float4*)&GLDS[row*GST + 4*l];
      float gi = gv.x, gf = gv.y, gg = gv.z, go = gv.w;
      const int s  = rowg >> 3;
      const int bb = rowg & 7;
      const int pos = s - WWIN + t;
      if (!L1){
        const int p0r = (pos < 0 ? 0 : pos)*8 + bb;
        const ushort4 pv = *(const ushort4*)&P0[(size_t)p0r*GDIM + 4*hd];
        gi += bf2f(pv.x); gf += bf2f(pv.y); gg += bf2f(pv.z); go += bf2f(pv.w);
      } else {
        float4 bv = *(const float4*)&br1[4*hd];
        gi += bv.x; gf += bv.y; gg += bv.z; go += bv.w;
      }
      const size_t sidx = (size_t)rowg*HDIM + hd;
      float cp = cbuf[sidx];
      float i_ = sigm(gi), f_ = sigm(gf), g_ = tanh_f(gg), o_ = sigm(go);
      float cn = f_*cp + i_*g_;
      float hn = o_*tanh_f(cn);
      if (pos < 0){ cn = 0.f; hn = 0.f; }
      cbuf[sidx] = cn;
      if (finalStep) out[sidx] = hn;
      else           hw[sidx]  = f2bf(hn);
    }
  }
}

extern "C" void kernel_launch(void* const* d_in, const int* in_sizes, int n_in,
                              void* d_out, int out_size, void* d_ws, size_t ws_size,
                              hipStream_t stream)
{
  const int*   enc  = (const int*)d_in[0];
  const float* tbl  = (const float*)d_in[1];
  const float* wih0 = (const float*)d_in[2];
  const float* whh0 = (const float*)d_in[3];
  const float* bih0 = (const float*)d_in[4];
  const float* bhh0 = (const float*)d_in[5];
  const float* wih1 = (const float*)d_in[6];
  const float* whh1 = (const float*)d_in[7];
  const float* bih1 = (const float*)d_in[8];
  const float* bhh1 = (const float*)d_in[9];
  float* out = (float*)d_out;

  char* ws = (char*)d_ws;
  size_t off = 0;
  auto alloc = [&](size_t bytes){
    char* p = ws + off; off += (bytes + 255) & ~(size_t)255; return p;
  };
  unsigned short* E     = (unsigned short*)alloc((size_t)NROWS*512*2);
  unsigned short* BrIh0 = (unsigned short*)alloc((size_t)GDIM*512*2);
  unsigned short* Br0   = (unsigned short*)alloc((size_t)GDIM*512*2);
  unsigned short* Br1   = (unsigned short*)alloc((size_t)GDIM*1024*2);
  float* bias0r = (float*)alloc(GDIM*4);
  float* br1    = (float*)alloc(GDIM*4);
  unsigned short* P0 = (unsigned short*)alloc((size_t)NROWS*GDIM*2);  // bf16 now
  unsigned short* h0 = (unsigned short*)alloc((size_t)2*NROWS*HDIM*2);
  unsigned short* h1 = (unsigned short*)alloc((size_t)2*NROWS*HDIM*2);
  float* c0 = (float*)alloc((size_t)NROWS*HDIM*4);   // fallback path only
  float* c1 = (float*)alloc((size_t)NROWS*HDIM*4);   // fallback path only
  unsigned* bar = (unsigned*)alloc(256);
  if (off > ws_size) return;  // workspace too small — would need fallback

  (void)hipFuncSetAttribute(reinterpret_cast<const void*>(persist_kernel),
                            hipFuncAttributeMaxDynamicSharedMemorySize, 131072);
  (void)hipFuncSetAttribute(reinterpret_cast<const void*>(step_kernel),
                            hipFuncAttributeMaxDynamicSharedMemorySize, 131072);

  // zero h0,h1,c0,c1,bar (contiguous: 8+8+8+8 MB + 256 B)
  hipMemsetAsync(h0, 0, (size_t)33554688, stream);

  prep_weights<<<2048, 256, 0, stream>>>(wih0, whh0, bih0, bhh0,
                                         wih1, whh1, bih1, bhh1,
                                         BrIh0, Br0, Br1, bias0r, br1);
  gather_embed<<<4096, 256, 0, stream>>>(enc, tbl, E);
  p0_gemm<<<512, 256, 0, stream>>>(E, BrIh0, bias0r, P0);

  int occ = 0;
  hipError_t oe = hipOccupancyMaxActiveBlocksPerMultiprocessor(
      &occ, reinterpret_cast<const void*>(persist_kernel), 512, 131072);
  bool coop = (oe == hipSuccess && occ >= 1);
  if (coop){
    void* kargs[] = {&h0, &h1, &Br0, &Br1, &P0, &br1, &out, &bar};
    hipError_t le = hipLaunchCooperativeKernel(
        reinterpret_cast<const void*>(persist_kernel),
        dim3(256), dim3(512), kargs, 131072, stream);
    if (le != hipSuccess) coop = false;
  }
  if (!coop){
    for (int tau = 0; tau <= 33; ++tau){
      const int grid = (tau == 0 || tau == 33) ? 128 : 256;
      const int boff = (tau == 33) ? 128 : 0;
      step_kernel<<<grid, 512, 131072, stream>>>(h0, h1, c0, c1, Br0, Br1,
                                                 P0, br1, out, tau, boff);
    }
  }
}

// Round 3
// 1738.817 us; speedup vs baseline: 1.0014x; 1.0014x over previous
//
#include <hip/hip_runtime.h>
#include <stdint.h>

#define NROWS 4096   // S*B
#define HDIM  512
#define GDIM  2048   // 4*H
#define WWIN  32

typedef __attribute__((ext_vector_type(8))) short short8;
typedef __attribute__((ext_vector_type(4))) float f32x4;

__device__ __forceinline__ unsigned short f2bf(float x){
  union { float f; unsigned int u; } v; v.f = x;
  unsigned int u = v.u + 0x7fffu + ((v.u >> 16) & 1u);
  return (unsigned short)(u >> 16);
}
__device__ __forceinline__ float bf2f(unsigned short u){
  union { unsigned int u; float f; } v; v.u = ((unsigned int)u) << 16; return v.f;
}

__device__ __forceinline__ void gld16(const void* g, void* l){
  __builtin_amdgcn_global_load_lds(
      (const __attribute__((address_space(1))) unsigned int*)g,
      (__attribute__((address_space(3))) unsigned int*)l, 16, 0, 0);
}

__device__ __forceinline__ float sigm(float x){ return 1.f/(1.f + __expf(-x)); }
__device__ __forceinline__ float tanh_f(float x){ return 1.f - 2.f/(1.f + __expf(2.f*x)); }

// ---- FENCE-FREE device-scope grid barrier -----------------------------------
// All cross-block data (h) moves via agent-scope atomics which are coherent by
// construction (bypass non-coherent per-XCD L2). So the barrier needs NO
// acquire/release cache fences -> L2 contents (weights, P0) survive across
// steps. __syncthreads drains each wave's vmcnt (stores complete at coherence
// point) before arrival.
__device__ __forceinline__ void grid_sync(unsigned* bar, unsigned target){
  __syncthreads();
  if (threadIdx.x == 0){
    unsigned arrived = __hip_atomic_fetch_add(&bar[0], 1u, __ATOMIC_RELAXED,
                                              __HIP_MEMORY_SCOPE_AGENT);
    if (arrived == gridDim.x - 1){
      __hip_atomic_store(&bar[0], 0u, __ATOMIC_RELAXED, __HIP_MEMORY_SCOPE_AGENT);
      __hip_atomic_store(&bar[1], target, __ATOMIC_RELAXED, __HIP_MEMORY_SCOPE_AGENT);
    } else {
      while (__hip_atomic_load(&bar[1], __ATOMIC_RELAXED, __HIP_MEMORY_SCOPE_AGENT) < target)
        __builtin_amdgcn_s_sleep(8);
    }
  }
  asm volatile("" ::: "memory");
  __syncthreads();
}

// ------------- double-buffered 128x128 GEMM core (bf16, BT weight layout) -----
// (p0_gemm only)
__device__ __forceinline__ void gemm_tile_db(
    const char* A0, const char* A1, const char* Bsrc,
    int ldbB, int nk, int r0, int c0,
    char* smem, int wr, int wc, int lane, f32x4 acc[4][4])
{
  const int tid = threadIdx.x;
  const int oo0 = tid * 16;
  const int srow = oo0 >> 7;
  const int scb  = oo0 & 127;
  const size_t aOff = (size_t)(r0 + srow) * 1024 + scb;
  const size_t bOff = (size_t)(c0 + srow) * (size_t)ldbB + scb;

  auto STAGE = [&](int kk, int buf){
    const char* Ap = (kk < 8) ? A0 : A1;
    const size_t kbA = (size_t)(kk & 7) * 128;
    const size_t kbB = (size_t)kk * 128;
    char* AsB = smem + buf * 16384;
    char* BsB = smem + 32768 + buf * 16384;
    #pragma unroll
    for (int i = 0; i < 4; ++i){
      const size_t rstep = (size_t)i * 32;
      gld16(Ap   + aOff + rstep * 1024          + kbA, AsB + i*4096 + oo0);
      gld16(Bsrc + bOff + rstep * (size_t)ldbB  + kbB, BsB + i*4096 + oo0);
    }
  };

  STAGE(0, 0);
  __syncthreads();

  const int lr = lane & 15;
  const int lk = (lane >> 4) * 8;

  for (int kk = 0; kk < nk; ++kk){
    const int cur = kk & 1;
    if (kk + 1 < nk) STAGE(kk + 1, cur ^ 1);

    const unsigned short* As = (const unsigned short*)(smem + cur*16384);
    const unsigned short* Bs = (const unsigned short*)(smem + 32768 + cur*16384);
    short8 a[2][4], b[2][4];
    #pragma unroll
    for (int h = 0; h < 2; ++h){
      const int k32 = h * 32;
      #pragma unroll
      for (int m = 0; m < 4; ++m)
        a[h][m] = *(const short8*)(As + (64*wr + 16*m + lr)*64 + k32 + lk);
      #pragma unroll
      for (int n = 0; n < 4; ++n)
        b[h][n] = *(const short8*)(Bs + (64*wc + 16*n + lr)*64 + k32 + lk);
    }
    __builtin_amdgcn_s_setprio(1);
    #pragma unroll
    for (int h = 0; h < 2; ++h)
      #pragma unroll
      for (int m = 0; m < 4; ++m)
        #pragma unroll
        for (int n = 0; n < 4; ++n)
          acc[m][n] = __builtin_amdgcn_mfma_f32_16x16x32_bf16(a[h][m], b[h][n], acc[m][n], 0, 0, 0);
    __builtin_amdgcn_s_setprio(0);

    __syncthreads();
  }
}

// ---------------- prep: reorder weights gate-interleaved, cast bf16 -----------
__global__ void __launch_bounds__(256) prep_weights(
    const float* wih0, const float* whh0, const float* bih0, const float* bhh0,
    const float* wih1, const float* whh1, const float* bih1, const float* bhh1,
    unsigned short* BrIh0, unsigned short* Br0, unsigned short* Br1,
    float* bias0r, float* br1)
{
  const int j = blockIdx.x;
  const int g = j & 3, hd = j >> 2;
  const int r = g*512 + hd;
  for (int k = threadIdx.x; k < 512; k += 256){
    BrIh0[(size_t)j*512 + k]      = f2bf(wih0[(size_t)r*512 + k]);
    Br0  [(size_t)j*512 + k]      = f2bf(whh0[(size_t)r*512 + k]);
    Br1  [(size_t)j*1024 + k]     = f2bf(wih1[(size_t)r*512 + k]);
    Br1  [(size_t)j*1024 + 512+k] = f2bf(whh1[(size_t)r*512 + k]);
  }
  if (threadIdx.x == 0){
    bias0r[j] = bih0[r] + bhh0[r];
    br1[j]    = bih1[r] + bhh1[r];
  }
}

// ---------------- embedding gather (fp32 -> bf16) -----------------------------
__global__ void __launch_bounds__(256) gather_embed(const int* enc, const float* tbl,
                                                    unsigned short* E)
{
  const int n = blockIdx.x;
  const int idx = enc[n];
  const float* src = tbl + (size_t)idx * 512;
  unsigned short* dst = E + (size_t)n * 512;
  for (int e = threadIdx.x; e < 512; e += 256) dst[e] = f2bf(src[e]);
}

// ---------------- P0 = E @ BrIh0^T + bias0r (bf16 out, interleaved cols) ------
__global__ void __launch_bounds__(256) p0_gemm(const unsigned short* E,
                                               const unsigned short* BrIh0,
                                               const float* bias0r,
                                               unsigned short* P0)
{
  __shared__ __align__(16) char smem[65536];
  const int tid  = threadIdx.x;
  const int lane = tid & 63, wid = tid >> 6;
  const int wr = wid >> 1, wc = wid & 1;
  const int bid = blockIdx.x;
  const int r0 = (bid >> 4) * 128, c0 = (bid & 15) * 128;
  f32x4 acc[4][4] = {};
  gemm_tile_db((const char*)E, nullptr, (const char*)BrIh0, 1024, 8,
               r0, c0, smem, wr, wc, lane, acc);
  #pragma unroll
  for (int m = 0; m < 4; ++m){
    const int rowb = r0 + 64*wr + 16*m + ((lane >> 4) << 2);
    #pragma unroll
    for (int n = 0; n < 4; ++n){
      const int colb = c0 + 64*wc + 16*n + (lane & 15);
      const float bs = bias0r[colb];
      #pragma unroll
      for (int r = 0; r < 4; ++r)
        P0[(size_t)(rowb + r)*GDIM + colb] = f2bf(acc[m][n][r] + bs);
    }
  }
}

// ============== persistent fused kernel: all 33 steps, both layers ============
// 256 blocks x 512 thr, 1 block/CU (96KB LDS). c-state in registers.
// Single-phase K-step: {12 ds_read -> issue B gld16 -> 32 MFMA -> vmcnt(2) ->
// ds_write A(kt+1) (reg-staged via agent atomics) -> issue A(kt+2) -> barrier}.
// B ring-4 (L2-hit after step 1: weights per XCD = 3MB < 4MB L2 via the
// rowg-quartet x colg-quartet XCD mapping). h moves ONLY via agent atomics ->
// grid barrier needs no cache fences -> L2 never invalidated.
__global__ void __launch_bounds__(512, 2) persist_kernel(
    unsigned short* h0, unsigned short* h1,
    const unsigned short* Br0, const unsigned short* Br1,
    const unsigned short* P0, const float* br1, float* out, unsigned* bar)
{
  extern __shared__ __align__(16) char smem[];

  // XCD mapping (bid%8 round-robin heuristic): XCD x gets rowg-quartet
  // (x>>1)*4.. and colg-quartet (x&1)*4.., both layers (32 blocks).
  const int bid = blockIdx.x;
  const int x = bid & 7, i = bid >> 3;
  const bool L1 = (i & 1);
  const int rowg = (x >> 1) * 4 + ((i >> 1) & 3);
  const int colg = (x & 1) * 4 + ((i >> 3) & 3);
  const int r0  = rowg * 256;
  const int c0v = colg * 256;

  const int tid  = threadIdx.x;
  const int lane = tid & 63, wid = tid >> 6;
  const int wm = wid >> 2, wn = wid & 3;
  const int lr = lane & 15, sl = lane >> 4;
  const int ph = (sl ^ ((lr >> 1) & 3)) << 4;   // swizzled ds_read slot

  // B staging (gld16, linear dest + inverse-swizzled source)
  const int srowB  = tid >> 2;
  const int sbyteB = ((tid & 3) ^ ((tid >> 3) & 3)) << 4;
  // A staging (regs): thread covers row ar, logical 16B slots as0, as0+1
  const int ar   = tid >> 1;
  const int as0  = (tid & 1) * 2;
  const int akey = (ar >> 1) & 3;

  const char* Bp  = (const char*)(L1 ? Br1 : Br0);
  const int  ldbB = L1 ? 2048 : 1024;
  const int  nkt  = L1 ? 32 : 16;

  float creg[4][4][2];
  #pragma unroll
  for (int p = 0; p < 4; ++p)
    #pragma unroll
    for (int q = 0; q < 4; ++q){ creg[p][q][0] = 0.f; creg[p][q][1] = 0.f; }

  for (int tau = 0; tau <= 33; ++tau){
    const bool active = L1 ? (tau >= 1) : (tau <= 32);
    if (active){
      const int t  = L1 ? (tau - 1) : tau;
      const int pr = (tau + 1) & 1, pw = tau & 1;
      const unsigned short* hA0 = h0 + (size_t)pr * (NROWS*HDIM);
      const unsigned short* hA1 = h1 + (size_t)pr * (NROWS*HDIM);

      auto issueB = [&](int kt2){
        const char* s0 = Bp + (size_t)(c0v + srowB) * (size_t)ldbB + kt2*64 + sbyteB;
        char* d = smem + 32768 + (size_t)(kt2 & 3) * 16384 + tid * 16;
        gld16(s0, d);
        gld16(s0 + (size_t)128 * (size_t)ldbB, d + 8192);
      };
      auto issueA = [&](int kt2, unsigned long long a[4]){
        const unsigned short* hs; int kE;
        if (!L1 || kt2 < 16){ hs = hA0; kE = kt2 * 32; }
        else                { hs = hA1; kE = (kt2 - 16) * 32; }
        unsigned long long* p = (unsigned long long*)(hs + (size_t)(r0 + ar) * 512 + kE + as0 * 8);
        a[0] = __hip_atomic_load(p+0, __ATOMIC_RELAXED, __HIP_MEMORY_SCOPE_AGENT);
        a[1] = __hip_atomic_load(p+1, __ATOMIC_RELAXED, __HIP_MEMORY_SCOPE_AGENT);
        a[2] = __hip_atomic_load(p+2, __ATOMIC_RELAXED, __HIP_MEMORY_SCOPE_AGENT);
        a[3] = __hip_atomic_load(p+3, __ATOMIC_RELAXED, __HIP_MEMORY_SCOPE_AGENT);
      };
      auto writeA = [&](int kt2, const unsigned long long a[4]){
        // ds_write_b64 x4 (4-way banked; b128 here would be 8-way conflicted)
        char* base = smem + (size_t)(kt2 & 1) * 16384 + ar * 64;
        char* p0 = base + ((as0 ^ akey) << 4);
        char* p1 = base + (((as0 + 1) ^ akey) << 4);
        *(unsigned long long*)(p0)     = a[0];
        *(unsigned long long*)(p0 + 8) = a[1];
        *(unsigned long long*)(p1)     = a[2];
        *(unsigned long long*)(p1 + 8) = a[3];
      };

      f32x4 acc[8][4] = {};
      unsigned long long areg[4];

      // prologue: A(0) via regs, B(0),B(1) via gld16
      issueA(0, areg);
      issueB(0); issueB(1);
      asm volatile("s_waitcnt vmcnt(4)" ::: "memory");   // A(0) done
      writeA(0, areg);
      issueA(1, areg);
      asm volatile("s_waitcnt vmcnt(4)" ::: "memory");   // B(0),B(1) done; A(1) flying
      asm volatile("s_waitcnt lgkmcnt(0)" ::: "memory");
      __builtin_amdgcn_s_barrier();

      for (int kt = 0; kt < nkt; ++kt){
        const char* Ab = smem + (size_t)(kt & 1) * 16384;
        const char* Bb = smem + 32768 + (size_t)(kt & 3) * 16384;
        short8 a[8], b[4];
        #pragma unroll
        for (int m = 0; m < 8; ++m)
          a[m] = *(const short8*)(Ab + (wm*128 + m*16 + lr)*64 + ph);
        #pragma unroll
        for (int n = 0; n < 4; ++n)
          b[n] = *(const short8*)(Bb + (wn*64 + n*16 + lr)*64 + ph);

        const bool stB = (kt + 2) < nkt;
        if (stB) issueB(kt + 2);

        __builtin_amdgcn_s_setprio(1);
        #pragma unroll
        for (int m = 0; m < 8; ++m)
          #pragma unroll
          for (int n = 0; n < 4; ++n)
            acc[m][n] = __builtin_amdgcn_mfma_f32_16x16x32_bf16(a[m], b[n], acc[m][n], 0, 0, 0);
        __builtin_amdgcn_s_setprio(0);

        if (stB) asm volatile("s_waitcnt vmcnt(2)" ::: "memory"); // A(kt+1),B(kt+1) done
        else     asm volatile("s_waitcnt vmcnt(0)" ::: "memory");
        if (kt + 1 < nkt){
          writeA(kt + 1, areg);
          if (kt + 2 < nkt) issueA(kt + 2, areg);
        }
        asm volatile("s_waitcnt lgkmcnt(0)" ::: "memory");
        __builtin_amdgcn_s_barrier();
      }

      // ---- epilogue: LSTM pointwise, c in regs, h via agent-atomic u32 ----
      float* GLDS = (float*)smem;
      const int GST = 68;
      unsigned short* hw = (L1 ? h1 : h0) + (size_t)pw * (NROWS*HDIM);
      const bool finalStep = (L1 && t == 32);
      const int cbase = c0v >> 2;

      #pragma unroll
      for (int pass = 0; pass < 4; ++pass){
        __syncthreads();
        if (wn == pass){
          #pragma unroll
          for (int m = 0; m < 8; ++m){
            const int rowb = wm*128 + m*16 + (sl << 2);
            #pragma unroll
            for (int n = 0; n < 4; ++n){
              const int colb = n*16 + lr;
              const f32x4 v = acc[m][n];
              #pragma unroll
              for (int r = 0; r < 4; ++r)
                GLDS[(rowb + r)*GST + colb] = v[r];
            }
          }
        }
        __syncthreads();
        #pragma unroll
        for (int it = 0; it < 4; ++it){
          const int pid = it*512 + tid;          // 2048 hd-pairs: 256 rows x 8
          const int row = pid >> 3;
          const int pl  = (pid & 7) * 2;
          const int rowg = r0 + row;
          const int hd0  = cbase + pass*16 + pl;
          const float* gp = &GLDS[row*GST + 4*pl];
          const float4 g0 = *(const float4*)gp;
          const float4 g1 = *(const float4*)(gp + 4);
          float gi0 = g0.x, gf0 = g0.y, gg0 = g0.z, go0 = g0.w;
          float gi1 = g1.x, gf1 = g1.y, gg1 = g1.z, go1 = g1.w;
          const int s  = rowg >> 3;
          const int bb = rowg & 7;
          const int pos = s - WWIN + t;
          if (!L1){
            const int p0r = (pos < 0 ? 0 : pos)*8 + bb;
            const uint4 pv = *(const uint4*)&P0[(size_t)p0r*GDIM + 4*hd0];
            gi0 += bf2f((unsigned short)(pv.x & 0xffff));
            gf0 += bf2f((unsigned short)(pv.x >> 16));
            gg0 += bf2f((unsigned short)(pv.y & 0xffff));
            go0 += bf2f((unsigned short)(pv.y >> 16));
            gi1 += bf2f((unsigned short)(pv.z & 0xffff));
            gf1 += bf2f((unsigned short)(pv.z >> 16));
            gg1 += bf2f((unsigned short)(pv.w & 0xffff));
            go1 += bf2f((unsigned short)(pv.w >> 16));
          } else {
            const float4 b0 = *(const float4*)&br1[4*hd0];
            const float4 b1 = *(const float4*)&br1[4*hd0 + 4];
            gi0 += b0.x; gf0 += b0.y; gg0 += b0.z; go0 += b0.w;
            gi1 += b1.x; gf1 += b1.y; gg1 += b1.z; go1 += b1.w;
          }
          float cp0 = creg[pass][it][0];
          float cp1 = creg[pass][it][1];
          float i0 = sigm(gi0), f0 = sigm(gf0), gA = tanh_f(gg0), o0 = sigm(go0);
          float i1 = sigm(gi1), f1 = sigm(gf1), gB = tanh_f(gg1), o1 = sigm(go1);
          float cn0 = f0*cp0 + i0*gA;
          float cn1 = f1*cp1 + i1*gB;
          float hn0 = o0*tanh_f(cn0);
          float hn1 = o1*tanh_f(cn1);
          if (pos < 0){ cn0 = 0.f; hn0 = 0.f; cn1 = 0.f; hn1 = 0.f; }
          creg[pass][it][0] = cn0;
          creg[pass][it][1] = cn1;
          const size_t sidx0 = (size_t)rowg*HDIM + hd0;
          if (finalStep){
            *(float2*)&out[sidx0] = make_float2(hn0, hn1);
          } else {
            const unsigned hp = (unsigned)f2bf(hn0) | ((unsigned)f2bf(hn1) << 16);
            __hip_atomic_store((unsigned*)&hw[sidx0], hp, __ATOMIC_RELAXED,
                               __HIP_MEMORY_SCOPE_AGENT);
          }
        }
      }
    }
    if (tau != 33) grid_sync(bar, (unsigned)(tau + 1));
  }
}

// ---------------- fallback per-step kernel (non-cooperative path) -------------
__global__ void __launch_bounds__(512, 2) step_kernel(
    unsigned short* h0, unsigned short* h1, float* c0b, float* c1b,
    const unsigned short* Br0, const unsigned short* Br1,
    const unsigned short* P0, const float* br1, float* out, int tau, int bidOff)
{
  extern __shared__ __align__(16) char smem[];

  const int x = blockIdx.x & 7, kq = blockIdx.x >> 3;
  int wk;
  if (gridDim.x == 256) wk = ((kq & 1) << 7) + x * 16 + (kq >> 1);
  else                  wk = x * 16 + kq;
  wk += bidOff;

  const bool L1 = (wk >= 128);
  const int t  = L1 ? (tau - 1) : tau;
  const int pr = (tau + 1) & 1, pw = tau & 1;
  const int lb = L1 ? (wk - 128) : wk;
  const int r0  = (lb >> 3) * 256;
  const int c0v = (lb & 7) * 256;

  const int tid  = threadIdx.x;
  const int lane = tid & 63;
  const int wid  = tid >> 6;
  const int wm = wid >> 2, wn = wid & 3;
  const int lr = lane & 15, sl = lane >> 4;

  const unsigned short* hA0 = h0 + (size_t)pr * (NROWS*HDIM);
  const unsigned short* hA1 = h1 + (size_t)pr * (NROWS*HDIM);
  const char* Bp  = (const char*)(L1 ? Br1 : Br0);
  const int  ldbB = L1 ? 2048 : 1024;
  const int  nkt  = L1 ? 32 : 16;

  const int srow  = tid >> 2;
  const int sbyte = ((tid & 3) ^ ((tid >> 3) & 3)) << 4;
  const int ph    = (sl ^ ((lr >> 1) & 3)) << 4;
  const int laneA = (wm*128 + lr) * 64 + ph;
  const int laneB = (wn*64  + lr) * 64 + ph;

  auto STAGE_A = [&](int kt2, int c){
    const char* Ap; int kB;
    if (!L1 || kt2 < 16){ Ap = (const char*)hA0; kB = kt2 * 64; }
    else                { Ap = (const char*)hA1; kB = (kt2 - 16) * 64; }
    gld16(Ap + (size_t)(r0 + c*128 + srow) * 1024 + kB + sbyte,
          smem + (size_t)(kt2 & 3) * 32768 + c*8192 + tid*16);
  };
  auto STAGE_B = [&](int kt2, int c){
    gld16(Bp + (size_t)(c0v + c*128 + srow) * (size_t)ldbB + kt2*64 + sbyte,
          smem + (size_t)(kt2 & 3) * 32768 + 16384 + c*8192 + tid*16);
  };

  f32x4 acc[8][4] = {};

  STAGE_A(0,0); STAGE_A(0,1); STAGE_B(0,0); STAGE_B(0,1);
  STAGE_A(1,0); STAGE_A(1,1); STAGE_B(1,0); STAGE_B(1,1);
  asm volatile("s_waitcnt vmcnt(4)" ::: "memory");
  __builtin_amdgcn_s_barrier();

  for (int kt = 0; kt < nkt; ++kt){
    const char* bufp = smem + (size_t)(kt & 3) * 32768;
    const bool st = (kt + 2) < nkt;
    short8 a0[4], a1[4], b[4];

    #pragma unroll
    for (int m = 0; m < 4; ++m) a0[m] = *(const short8*)(bufp + laneA + m*1024);
    #pragma unroll
    for (int n = 0; n < 4; ++n) b[n]  = *(const short8*)(bufp + 16384 + laneB + n*1024);
    if (st){ STAGE_A(kt+2, 0); STAGE_A(kt+2, 1); }
    __builtin_amdgcn_s_barrier();
    asm volatile("s_waitcnt lgkmcnt(0)" ::: "memory");
    __builtin_amdgcn_sched_barrier(0);
    __builtin_amdgcn_s_setprio(1);
    #pragma unroll
    for (int m = 0; m < 4; ++m)
      #pragma unroll
      for (int n = 0; n < 4; ++n)
        acc[m][n] = __builtin_amdgcn_mfma_f32_16x16x32_bf16(a0[m], b[n], acc[m][n], 0, 0, 0);
    __builtin_amdgcn_s_setprio(0);
    __builtin_amdgcn_s_barrier();

    #pragma unroll
    for (int m = 0; m < 4; ++m) a1[m] = *(const short8*)(bufp + laneA + (4+m)*1024);
    if (st){
      STAGE_B(kt+2, 0); STAGE_B(kt+2, 1);
      asm volatile("s_waitcnt vmcnt(4)" ::: "memory");
    } else {
      asm volatile("s_waitcnt vmcnt(0)" ::: "memory");
    }
    __builtin_amdgcn_s_barrier();
    asm volatile("s_waitcnt lgkmcnt(0)" ::: "memory");
    __builtin_amdgcn_sched_barrier(0);
    __builtin_amdgcn_s_setprio(1);
    #pragma unroll
    for (int m = 0; m < 4; ++m)
      #pragma unroll
      for (int n = 0; n < 4; ++n)
        acc[4+m][n] = __builtin_amdgcn_mfma_f32_16x16x32_bf16(a1[m], b[n], acc[4+m][n], 0, 0, 0);
    __builtin_amdgcn_s_setprio(0);
    __builtin_amdgcn_s_barrier();
  }

  float* GLDS = (float*)smem;
  const int GST = 68;
  float* cbuf = L1 ? c1b : c0b;
  unsigned short* hw = (L1 ? h1 : h0) + (size_t)pw * (NROWS*HDIM);
  const bool finalStep = (L1 && t == 32);

  for (int pass = 0; pass < 4; ++pass){
    __syncthreads();
    if (wn == pass){
      #pragma unroll
      for (int m = 0; m < 8; ++m){
        const int rowb = wm*128 + m*16 + (sl << 2);
        #pragma unroll
        for (int n = 0; n < 4; ++n){
          const int colb = n*16 + lr;
          const f32x4 v = acc[m][n];
          #pragma unroll
          for (int r = 0; r < 4; ++r)
            GLDS[(rowb + r)*GST + colb] = v[r];
        }
      }
    }
    __syncthreads();
    #pragma unroll
    for (int it = 0; it < 8; ++it){
      const int cid = it*512 + tid;
      const int row = cid >> 4;
      const int l   = cid & 15;
      const int rowg = r0 + row;
      const int hd   = (c0v >> 2) + pass*16 + l;
      float4 gv = *(const float4*)&GLDS[row*GST + 4*l];
      float gi = gv.x, gf = gv.y, gg = gv.z, go = gv.w;
      const int s  = rowg >> 3;
      const int bb = rowg & 7;
      const int pos = s - WWIN + t;
      if (!L1){
        const int p0r = (pos < 0 ? 0 : pos)*8 + bb;
        const ushort4 pv = *(const ushort4*)&P0[(size_t)p0r*GDIM + 4*hd];
        gi += bf2f(pv.x); gf += bf2f(pv.y); gg += bf2f(pv.z); go += bf2f(pv.w);
      } else {
        float4 bv = *(const float4*)&br1[4*hd];
        gi += bv.x; gf += bv.y; gg += bv.z; go += bv.w;
      }
      const size_t sidx = (size_t)rowg*HDIM + hd;
      float cp = cbuf[sidx];
      float i_ = sigm(gi), f_ = sigm(gf), g_ = tanh_f(gg), o_ = sigm(go);
      float cn = f_*cp + i_*g_;
      float hn = o_*tanh_f(cn);
      if (pos < 0){ cn = 0.f; hn = 0.f; }
      cbuf[sidx] = cn;
      if (finalStep) out[sidx] = hn;
      else           hw[sidx]  = f2bf(hn);
    }
  }
}

extern "C" void kernel_launch(void* const* d_in, const int* in_sizes, int n_in,
                              void* d_out, int out_size, void* d_ws, size_t ws_size,
                              hipStream_t stream)
{
  const int*   enc  = (const int*)d_in[0];
  const float* tbl  = (const float*)d_in[1];
  const float* wih0 = (const float*)d_in[2];
  const float* whh0 = (const float*)d_in[3];
  const float* bih0 = (const float*)d_in[4];
  const float* bhh0 = (const float*)d_in[5];
  const float* wih1 = (const float*)d_in[6];
  const float* whh1 = (const float*)d_in[7];
  const float* bih1 = (const float*)d_in[8];
  const float* bhh1 = (const float*)d_in[9];
  float* out = (float*)d_out;

  char* ws = (char*)d_ws;
  size_t off = 0;
  auto alloc = [&](size_t bytes){
    char* p = ws + off; off += (bytes + 255) & ~(size_t)255; return p;
  };
  unsigned short* E     = (unsigned short*)alloc((size_t)NROWS*512*2);
  unsigned short* BrIh0 = (unsigned short*)alloc((size_t)GDIM*512*2);
  unsigned short* Br0   = (unsigned short*)alloc((size_t)GDIM*512*2);
  unsigned short* Br1   = (unsigned short*)alloc((size_t)GDIM*1024*2);
  float* bias0r = (float*)alloc(GDIM*4);
  float* br1    = (float*)alloc(GDIM*4);
  unsigned short* P0 = (unsigned short*)alloc((size_t)NROWS*GDIM*2);
  unsigned short* h0 = (unsigned short*)alloc((size_t)2*NROWS*HDIM*2);
  unsigned short* h1 = (unsigned short*)alloc((size_t)2*NROWS*HDIM*2);
  float* c0 = (float*)alloc((size_t)NROWS*HDIM*4);   // fallback path only
  float* c1 = (float*)alloc((size_t)NROWS*HDIM*4);   // fallback path only
  unsigned* bar = (unsigned*)alloc(256);
  if (off > ws_size) return;  // workspace too small — would need fallback

  (void)hipFuncSetAttribute(reinterpret_cast<const void*>(persist_kernel),
                            hipFuncAttributeMaxDynamicSharedMemorySize, 98304);
  (void)hipFuncSetAttribute(reinterpret_cast<const void*>(step_kernel),
                            hipFuncAttributeMaxDynamicSharedMemorySize, 131072);

  // zero h0,h1,c0,c1,bar (contiguous: 8+8+8+8 MB + 256 B)
  hipMemsetAsync(h0, 0, (size_t)33554688, stream);

  prep_weights<<<2048, 256, 0, stream>>>(wih0, whh0, bih0, bhh0,
                                         wih1, whh1, bih1, bhh1,
                                         BrIh0, Br0, Br1, bias0r, br1);
  gather_embed<<<4096, 256, 0, stream>>>(enc, tbl, E);
  p0_gemm<<<512, 256, 0, stream>>>(E, BrIh0, bias0r, P0);

  int occ = 0;
  hipError_t oe = hipOccupancyMaxActiveBlocksPerMultiprocessor(
      &occ, reinterpret_cast<const void*>(persist_kernel), 512, 98304);
  bool coop = (oe == hipSuccess && occ >= 1);
  if (coop){
    void* kargs[] = {&h0, &h1, &Br0, &Br1, &P0, &br1, &out, &bar};
    hipError_t le = hipLaunchCooperativeKernel(
        reinterpret_cast<const void*>(persist_kernel),
        dim3(256), dim3(512), kargs, 98304, stream);
    if (le != hipSuccess) coop = false;
  }
  if (!coop){
    for (int tau = 0; tau <= 33; ++tau){
      const int grid = (tau == 0 || tau == 33) ? 128 : 256;
      const int boff = (tau == 33) ? 128 : 0;
      step_kernel<<<grid, 512, 131072, stream>>>(h0, h1, c0, c1, Br0, Br1,
                                                 P0, br1, out, tau, boff);
    }
  }
}

// Round 4
// 1737.768 us; speedup vs baseline: 1.0020x; 1.0006x over previous
//
#include <hip/hip_runtime.h>
#include <stdint.h>

#define NROWS 4096   // S*B
#define HDIM  512
#define GDIM  2048   // 4*H
#define WWIN  32

typedef __attribute__((ext_vector_type(8))) short short8;
typedef __attribute__((ext_vector_type(4))) float f32x4;

__device__ __forceinline__ unsigned short f2bf(float x){
  union { float f; unsigned int u; } v; v.f = x;
  unsigned int u = v.u + 0x7fffu + ((v.u >> 16) & 1u);
  return (unsigned short)(u >> 16);
}
__device__ __forceinline__ float bf2f(unsigned short u){
  union { unsigned int u; float f; } v; v.u = ((unsigned int)u) << 16; return v.f;
}

__device__ __forceinline__ void gld16(const void* g, void* l){
  __builtin_amdgcn_global_load_lds(
      (const __attribute__((address_space(1))) unsigned int*)g,
      (__attribute__((address_space(3))) unsigned int*)l, 16, 0, 0);
}

__device__ __forceinline__ float sigm(float x){ return 1.f/(1.f + __expf(-x)); }
__device__ __forceinline__ float tanh_f(float x){ return 1.f - 2.f/(1.f + __expf(2.f*x)); }

// ---- per-band sync: 16 blocks (8 L0 + 8 L1) share one monotonic counter -----
// h moves via agent-relaxed atomics (coherent at L3, bypasses L2) -> no cache
// fences needed; __syncthreads drains each wave's stores before arrival.
__device__ __forceinline__ void band_sync(unsigned* ctr, unsigned target){
  __syncthreads();
  if (threadIdx.x == 0){
    __hip_atomic_fetch_add(ctr, 1u, __ATOMIC_RELAXED, __HIP_MEMORY_SCOPE_AGENT);
    while (__hip_atomic_load(ctr, __ATOMIC_RELAXED, __HIP_MEMORY_SCOPE_AGENT) < target)
      __builtin_amdgcn_s_sleep(2);
  }
  asm volatile("" ::: "memory");
  __syncthreads();
}

// ------------- double-buffered 128x128 GEMM core (bf16, BT weight layout) -----
// (p0_gemm only)
__device__ __forceinline__ void gemm_tile_db(
    const char* A0, const char* A1, const char* Bsrc,
    int ldbB, int nk, int r0, int c0,
    char* smem, int wr, int wc, int lane, f32x4 acc[4][4])
{
  const int tid = threadIdx.x;
  const int oo0 = tid * 16;
  const int srow = oo0 >> 7;
  const int scb  = oo0 & 127;
  const size_t aOff = (size_t)(r0 + srow) * 1024 + scb;
  const size_t bOff = (size_t)(c0 + srow) * (size_t)ldbB + scb;

  auto STAGE = [&](int kk, int buf){
    const char* Ap = (kk < 8) ? A0 : A1;
    const size_t kbA = (size_t)(kk & 7) * 128;
    const size_t kbB = (size_t)kk * 128;
    char* AsB = smem + buf * 16384;
    char* BsB = smem + 32768 + buf * 16384;
    #pragma unroll
    for (int i = 0; i < 4; ++i){
      const size_t rstep = (size_t)i * 32;
      gld16(Ap   + aOff + rstep * 1024          + kbA, AsB + i*4096 + oo0);
      gld16(Bsrc + bOff + rstep * (size_t)ldbB  + kbB, BsB + i*4096 + oo0);
    }
  };

  STAGE(0, 0);
  __syncthreads();

  const int lr = lane & 15;
  const int lk = (lane >> 4) * 8;

  for (int kk = 0; kk < nk; ++kk){
    const int cur = kk & 1;
    if (kk + 1 < nk) STAGE(kk + 1, cur ^ 1);

    const unsigned short* As = (const unsigned short*)(smem + cur*16384);
    const unsigned short* Bs = (const unsigned short*)(smem + 32768 + cur*16384);
    short8 a[2][4], b[2][4];
    #pragma unroll
    for (int h = 0; h < 2; ++h){
      const int k32 = h * 32;
      #pragma unroll
      for (int m = 0; m < 4; ++m)
        a[h][m] = *(const short8*)(As + (64*wr + 16*m + lr)*64 + k32 + lk);
      #pragma unroll
      for (int n = 0; n < 4; ++n)
        b[h][n] = *(const short8*)(Bs + (64*wc + 16*n + lr)*64 + k32 + lk);
    }
    __builtin_amdgcn_s_setprio(1);
    #pragma unroll
    for (int h = 0; h < 2; ++h)
      #pragma unroll
      for (int m = 0; m < 4; ++m)
        #pragma unroll
        for (int n = 0; n < 4; ++n)
          acc[m][n] = __builtin_amdgcn_mfma_f32_16x16x32_bf16(a[h][m], b[h][n], acc[m][n], 0, 0, 0);
    __builtin_amdgcn_s_setprio(0);

    __syncthreads();
  }
}

// ---------------- prep: reorder weights gate-interleaved, cast bf16 -----------
__global__ void __launch_bounds__(256) prep_weights(
    const float* wih0, const float* whh0, const float* bih0, const float* bhh0,
    const float* wih1, const float* whh1, const float* bih1, const float* bhh1,
    unsigned short* BrIh0, unsigned short* Br0, unsigned short* Br1,
    float* bias0r, float* br1)
{
  const int j = blockIdx.x;
  const int g = j & 3, hd = j >> 2;
  const int r = g*512 + hd;
  for (int k = threadIdx.x; k < 512; k += 256){
    BrIh0[(size_t)j*512 + k]      = f2bf(wih0[(size_t)r*512 + k]);
    Br0  [(size_t)j*512 + k]      = f2bf(whh0[(size_t)r*512 + k]);
    Br1  [(size_t)j*1024 + k]     = f2bf(wih1[(size_t)r*512 + k]);
    Br1  [(size_t)j*1024 + 512+k] = f2bf(whh1[(size_t)r*512 + k]);
  }
  if (threadIdx.x == 0){
    bias0r[j] = bih0[r] + bhh0[r];
    br1[j]    = bih1[r] + bhh1[r];
  }
}

// ---------------- embedding gather (fp32 -> bf16) -----------------------------
__global__ void __launch_bounds__(256) gather_embed(const int* enc, const float* tbl,
                                                    unsigned short* E)
{
  const int n = blockIdx.x;
  const int idx = enc[n];
  const float* src = tbl + (size_t)idx * 512;
  unsigned short* dst = E + (size_t)n * 512;
  for (int e = threadIdx.x; e < 512; e += 256) dst[e] = f2bf(src[e]);
}

// ---------------- P0 = E @ BrIh0^T + bias0r (bf16 out, interleaved cols) ------
__global__ void __launch_bounds__(256) p0_gemm(const unsigned short* E,
                                               const unsigned short* BrIh0,
                                               const float* bias0r,
                                               unsigned short* P0)
{
  __shared__ __align__(16) char smem[65536];
  const int tid  = threadIdx.x;
  const int lane = tid & 63, wid = tid >> 6;
  const int wr = wid >> 1, wc = wid & 1;
  const int bid = blockIdx.x;
  const int r0 = (bid >> 4) * 128, c0 = (bid & 15) * 128;
  f32x4 acc[4][4] = {};
  gemm_tile_db((const char*)E, nullptr, (const char*)BrIh0, 1024, 8,
               r0, c0, smem, wr, wc, lane, acc);
  #pragma unroll
  for (int m = 0; m < 4; ++m){
    const int rowb = r0 + 64*wr + 16*m + ((lane >> 4) << 2);
    #pragma unroll
    for (int n = 0; n < 4; ++n){
      const int colb = c0 + 64*wc + 16*n + (lane & 15);
      const float bs = bias0r[colb];
      #pragma unroll
      for (int r = 0; r < 4; ++r)
        P0[(size_t)(rowb + r)*GDIM + colb] = f2bf(acc[m][n][r] + bs);
    }
  }
}

// ============== persistent fused kernel v2: 512 blocks, 2 per CU ==============
// Tile 128x256, 4 waves (1x4 over cols), 48KB LDS (A ring-2 8KB + B ring-2
// 16KB). colg = bid&7 -> per-XCD weight slice 3MB (L2-resident); each CU gets
// one L0 + one L1 block -> per-CU work balanced AND per-block barriers no
// longer lockstep the CU (cross-block phase drift overlaps LDS/MFMA/VALU
// pipes). c-state in regs. kt loop: plain ds_reads+MFMA (compiler-scheduled
// lgkmcnt), counted vmcnt(4) staging waits, raw s_barrier without vmcnt drain.
__global__ void __launch_bounds__(256, 2) persist_kernel(
    unsigned short* h0, unsigned short* h1,
    const unsigned short* Br0, const unsigned short* Br1,
    const unsigned short* P0, const float* br1, float* out, unsigned* bar)
{
  extern __shared__ __align__(16) char smem[];

  const int bid  = blockIdx.x;
  const int colg = bid & 7;          // XCD-resident weight slice
  const int bl   = bid >> 3;         // 0..63
  const bool L1  = (bl & 1);         // pair L0/L1 on neighboring blocks
  const int rb   = bl >> 1;          // 0..31 (128-row band)
  const int r0   = rb * 128;
  const int c0v  = colg * 256;

  const int tid  = threadIdx.x;
  const int lane = tid & 63, wid = tid >> 6;   // 4 waves
  const int wn = wid;                          // 1x4 wave grid over cols
  const int lr = lane & 15, sl = lane >> 4;
  const int ph = (sl ^ ((lr >> 1) & 3)) << 4;  // swizzled ds_read slot

  const int sbyteB = ((tid & 3) ^ ((tid >> 3) & 3)) << 4;  // inverse-swz source
  const int ar   = tid >> 1;          // A staging row 0..127
  const int as0  = (tid & 1) * 2;
  const int akey = (ar >> 1) & 3;

  const char* Bp  = (const char*)(L1 ? Br1 : Br0);
  const int  ldbB = L1 ? 2048 : 1024;
  const int  nkt  = L1 ? 32 : 16;

  unsigned* ctr = bar + rb * 32;      // 128B-padded per-band counter

  float creg[4][4][2];
  #pragma unroll
  for (int p = 0; p < 4; ++p)
    #pragma unroll
    for (int q = 0; q < 4; ++q){ creg[p][q][0] = 0.f; creg[p][q][1] = 0.f; }

  for (int tau = 0; tau <= 33; ++tau){
    const bool active = L1 ? (tau >= 1) : (tau <= 32);
    if (active){
      const int t  = L1 ? (tau - 1) : tau;
      const int pr = (tau + 1) & 1, pw = tau & 1;
      const unsigned short* hA0 = h0 + (size_t)pr * (NROWS*HDIM);
      const unsigned short* hA1 = h1 + (size_t)pr * (NROWS*HDIM);

      auto issueB = [&](int kt2){
        char* d = smem + 16384 + (size_t)(kt2 & 1) * 16384 + tid * 16;
        const char* s = Bp + (size_t)(c0v + (tid >> 2)) * (size_t)ldbB
                           + kt2 * 64 + sbyteB;
        #pragma unroll
        for (int i = 0; i < 4; ++i)
          gld16(s + (size_t)(i * 64) * (size_t)ldbB, d + i * 4096);
      };
      auto issueA = [&](int kt2, unsigned long long a[4]){
        const unsigned short* hs; int kE;
        if (!L1 || kt2 < 16){ hs = hA0; kE = kt2 * 32; }
        else                { hs = hA1; kE = (kt2 - 16) * 32; }
        const unsigned long long* p =
            (const unsigned long long*)(hs + (size_t)(r0 + ar) * 512 + kE + as0 * 8);
        a[0] = __hip_atomic_load(p+0, __ATOMIC_RELAXED, __HIP_MEMORY_SCOPE_AGENT);
        a[1] = __hip_atomic_load(p+1, __ATOMIC_RELAXED, __HIP_MEMORY_SCOPE_AGENT);
        a[2] = __hip_atomic_load(p+2, __ATOMIC_RELAXED, __HIP_MEMORY_SCOPE_AGENT);
        a[3] = __hip_atomic_load(p+3, __ATOMIC_RELAXED, __HIP_MEMORY_SCOPE_AGENT);
      };
      auto writeA = [&](int kt2, const unsigned long long a[4]){
        char* base = smem + (size_t)(kt2 & 1) * 8192 + ar * 64;
        char* p0 = base + ((as0 ^ akey) << 4);
        char* p1 = base + (((as0 + 1) ^ akey) << 4);
        *(unsigned long long*)(p0)     = a[0];
        *(unsigned long long*)(p0 + 8) = a[1];
        *(unsigned long long*)(p1)     = a[2];
        *(unsigned long long*)(p1 + 8) = a[3];
      };

      f32x4 acc[8][4] = {};
      unsigned long long areg[4];

      // prologue: A(0)->regs->LDS, B(0) in flight, A(1) in flight
      issueA(0, areg);
      issueB(0);
      writeA(0, areg);                 // compiler waits areg precisely
      issueA(1, areg);
      asm volatile("s_waitcnt vmcnt(4)" ::: "memory");   // B(0) landed
      asm volatile("s_waitcnt lgkmcnt(0)" ::: "memory");
      __builtin_amdgcn_s_barrier();

      for (int kt = 0; kt < nkt; ++kt){
        if (kt + 1 < nkt) issueB(kt + 1);
        const char* Ab = smem + (size_t)(kt & 1) * 8192;
        const char* Bb = smem + 16384 + (size_t)(kt & 1) * 16384;
        short8 a[8], b[4];
        #pragma unroll
        for (int n = 0; n < 4; ++n)
          b[n] = *(const short8*)(Bb + (wn*64 + n*16 + lr)*64 + ph);
        #pragma unroll
        for (int m = 0; m < 8; ++m)
          a[m] = *(const short8*)(Ab + (m*16 + lr)*64 + ph);

        __builtin_amdgcn_s_setprio(1);
        #pragma unroll
        for (int m = 0; m < 8; ++m)
          #pragma unroll
          for (int n = 0; n < 4; ++n)
            acc[m][n] = __builtin_amdgcn_mfma_f32_16x16x32_bf16(a[m], b[n], acc[m][n], 0, 0, 0);
        __builtin_amdgcn_s_setprio(0);

        if (kt + 1 < nkt){
          writeA(kt + 1, areg);        // compiler waits areg precisely
          if (kt + 2 < nkt){
            issueA(kt + 2, areg);
            asm volatile("s_waitcnt vmcnt(4)" ::: "memory");  // B(kt+1) landed
          } else {
            asm volatile("s_waitcnt vmcnt(0)" ::: "memory");
          }
          asm volatile("s_waitcnt lgkmcnt(0)" ::: "memory");
          __builtin_amdgcn_s_barrier();
        }
      }

      // ---- epilogue: LSTM pointwise, c in regs, h via agent-atomic u32 ----
      float* GLDS = (float*)smem;
      const int GST = 68;              // 128 x 68 x 4B = 34.8KB <= 48KB
      unsigned short* hw = (L1 ? h1 : h0) + (size_t)pw * (NROWS*HDIM);
      const bool finalStep = (L1 && t == 32);
      const int cbase = c0v >> 2;      // = colg*64

      #pragma unroll
      for (int pass = 0; pass < 4; ++pass){
        __syncthreads();
        if (wn == pass){
          #pragma unroll
          for (int m = 0; m < 8; ++m){
            const int rowb = m*16 + (sl << 2);
            #pragma unroll
            for (int n = 0; n < 4; ++n){
              const int colb = n*16 + lr;
              const f32x4 v = acc[m][n];
              #pragma unroll
              for (int r = 0; r < 4; ++r)
                GLDS[(rowb + r)*GST + colb] = v[r];
            }
          }
        }
        __syncthreads();
        #pragma unroll
        for (int it = 0; it < 4; ++it){
          const int pid = it*256 + tid;          // 1024 hd-pairs: 128 rows x 8
          const int row = pid >> 3;
          const int pl  = (pid & 7) * 2;
          const int rowg = r0 + row;
          const int hd0  = cbase + pass*16 + pl;
          const float* gp = &GLDS[row*GST + 4*pl];
          const float4 g0 = *(const float4*)gp;
          const float4 g1 = *(const float4*)(gp + 4);
          float gi0 = g0.x, gf0 = g0.y, gg0 = g0.z, go0 = g0.w;
          float gi1 = g1.x, gf1 = g1.y, gg1 = g1.z, go1 = g1.w;
          const int s  = rowg >> 3;
          const int bb = rowg & 7;
          const int pos = s - WWIN + t;
          if (!L1){
            const int p0r = (pos < 0 ? 0 : pos)*8 + bb;
            const uint4 pv = *(const uint4*)&P0[(size_t)p0r*GDIM + 4*hd0];
            gi0 += bf2f((unsigned short)(pv.x & 0xffff));
            gf0 += bf2f((unsigned short)(pv.x >> 16));
            gg0 += bf2f((unsigned short)(pv.y & 0xffff));
            go0 += bf2f((unsigned short)(pv.y >> 16));
            gi1 += bf2f((unsigned short)(pv.z & 0xffff));
            gf1 += bf2f((unsigned short)(pv.z >> 16));
            gg1 += bf2f((unsigned short)(pv.w & 0xffff));
            go1 += bf2f((unsigned short)(pv.w >> 16));
          } else {
            const float4 b0 = *(const float4*)&br1[4*hd0];
            const float4 b1 = *(const float4*)&br1[4*hd0 + 4];
            gi0 += b0.x; gf0 += b0.y; gg0 += b0.z; go0 += b0.w;
            gi1 += b1.x; gf1 += b1.y; gg1 += b1.z; go1 += b1.w;
          }
          float cp0 = creg[pass][it][0];
          float cp1 = creg[pass][it][1];
          float i0 = sigm(gi0), f0 = sigm(gf0), gA = tanh_f(gg0), o0 = sigm(go0);
          float i1 = sigm(gi1), f1 = sigm(gf1), gB = tanh_f(gg1), o1 = sigm(go1);
          float cn0 = f0*cp0 + i0*gA;
          float cn1 = f1*cp1 + i1*gB;
          float hn0 = o0*tanh_f(cn0);
          float hn1 = o1*tanh_f(cn1);
          if (pos < 0){ cn0 = 0.f; hn0 = 0.f; cn1 = 0.f; hn1 = 0.f; }
          creg[pass][it][0] = cn0;
          creg[pass][it][1] = cn1;
          const size_t sidx0 = (size_t)rowg*HDIM + hd0;
          if (finalStep){
            *(float2*)&out[sidx0] = make_float2(hn0, hn1);
          } else {
            const unsigned hp = (unsigned)f2bf(hn0) | ((unsigned)f2bf(hn1) << 16);
            __hip_atomic_store((unsigned*)&hw[sidx0], hp, __ATOMIC_RELAXED,
                               __HIP_MEMORY_SCOPE_AGENT);
          }
        }
      }
    }
    if (tau != 33) band_sync(ctr, 16u * (unsigned)(tau + 1));
  }
}

// ---------------- fallback per-step kernel (non-cooperative path) -------------
__global__ void __launch_bounds__(512, 2) step_kernel(
    unsigned short* h0, unsigned short* h1, float* c0b, float* c1b,
    const unsigned short* Br0, const unsigned short* Br1,
    const unsigned short* P0, const float* br1, float* out, int tau, int bidOff)
{
  extern __shared__ __align__(16) char smem[];

  const int x = blockIdx.x & 7, kq = blockIdx.x >> 3;
  int wk;
  if (gridDim.x == 256) wk = ((kq & 1) << 7) + x * 16 + (kq >> 1);
  else                  wk = x * 16 + kq;
  wk += bidOff;

  const bool L1 = (wk >= 128);
  const int t  = L1 ? (tau - 1) : tau;
  const int pr = (tau + 1) & 1, pw = tau & 1;
  const int lb = L1 ? (wk - 128) : wk;
  const int r0  = (lb >> 3) * 256;
  const int c0v = (lb & 7) * 256;

  const int tid  = threadIdx.x;
  const int lane = tid & 63;
  const int wid  = tid >> 6;
  const int wm = wid >> 2, wn = wid & 3;
  const int lr = lane & 15, sl = lane >> 4;

  const unsigned short* hA0 = h0 + (size_t)pr * (NROWS*HDIM);
  const unsigned short* hA1 = h1 + (size_t)pr * (NROWS*HDIM);
  const char* Bp  = (const char*)(L1 ? Br1 : Br0);
  const int  ldbB = L1 ? 2048 : 1024;
  const int  nkt  = L1 ? 32 : 16;

  const int srow  = tid >> 2;
  const int sbyte = ((tid & 3) ^ ((tid >> 3) & 3)) << 4;
  const int ph    = (sl ^ ((lr >> 1) & 3)) << 4;
  const int laneA = (wm*128 + lr) * 64 + ph;
  const int laneB = (wn*64  + lr) * 64 + ph;

  auto STAGE_A = [&](int kt2, int c){
    const char* Ap; int kB;
    if (!L1 || kt2 < 16){ Ap = (const char*)hA0; kB = kt2 * 64; }
    else                { Ap = (const char*)hA1; kB = (kt2 - 16) * 64; }
    gld16(Ap + (size_t)(r0 + c*128 + srow) * 1024 + kB + sbyte,
          smem + (size_t)(kt2 & 3) * 32768 + c*8192 + tid*16);
  };
  auto STAGE_B = [&](int kt2, int c){
    gld16(Bp + (size_t)(c0v + c*128 + srow) * (size_t)ldbB + kt2*64 + sbyte,
          smem + (size_t)(kt2 & 3) * 32768 + 16384 + c*8192 + tid*16);
  };

  f32x4 acc[8][4] = {};

  STAGE_A(0,0); STAGE_A(0,1); STAGE_B(0,0); STAGE_B(0,1);
  STAGE_A(1,0); STAGE_A(1,1); STAGE_B(1,0); STAGE_B(1,1);
  asm volatile("s_waitcnt vmcnt(4)" ::: "memory");
  __builtin_amdgcn_s_barrier();

  for (int kt = 0; kt < nkt; ++kt){
    const char* bufp = smem + (size_t)(kt & 3) * 32768;
    const bool st = (kt + 2) < nkt;
    short8 a0[4], a1[4], b[4];

    #pragma unroll
    for (int m = 0; m < 4; ++m) a0[m] = *(const short8*)(bufp + laneA + m*1024);
    #pragma unroll
    for (int n = 0; n < 4; ++n) b[n]  = *(const short8*)(bufp + 16384 + laneB + n*1024);
    if (st){ STAGE_A(kt+2, 0); STAGE_A(kt+2, 1); }
    __builtin_amdgcn_s_barrier();
    asm volatile("s_waitcnt lgkmcnt(0)" ::: "memory");
    __builtin_amdgcn_sched_barrier(0);
    __builtin_amdgcn_s_setprio(1);
    #pragma unroll
    for (int m = 0; m < 4; ++m)
      #pragma unroll
      for (int n = 0; n < 4; ++n)
        acc[m][n] = __builtin_amdgcn_mfma_f32_16x16x32_bf16(a0[m], b[n], acc[m][n], 0, 0, 0);
    __builtin_amdgcn_s_setprio(0);
    __builtin_amdgcn_s_barrier();

    #pragma unroll
    for (int m = 0; m < 4; ++m) a1[m] = *(const short8*)(bufp + laneA + (4+m)*1024);
    if (st){
      STAGE_B(kt+2, 0); STAGE_B(kt+2, 1);
      asm volatile("s_waitcnt vmcnt(4)" ::: "memory");
    } else {
      asm volatile("s_waitcnt vmcnt(0)" ::: "memory");
    }
    __builtin_amdgcn_s_barrier();
    asm volatile("s_waitcnt lgkmcnt(0)" ::: "memory");
    __builtin_amdgcn_sched_barrier(0);
    __builtin_amdgcn_s_setprio(1);
    #pragma unroll
    for (int m = 0; m < 4; ++m)
      #pragma unroll
      for (int n = 0; n < 4; ++n)
        acc[4+m][n] = __builtin_amdgcn_mfma_f32_16x16x32_bf16(a1[m], b[n], acc[4+m][n], 0, 0, 0);
    __builtin_amdgcn_s_setprio(0);
    __builtin_amdgcn_s_barrier();
  }

  float* GLDS = (float*)smem;
  const int GST = 68;
  float* cbuf = L1 ? c1b : c0b;
  unsigned short* hw = (L1 ? h1 : h0) + (size_t)pw * (NROWS*HDIM);
  const bool finalStep = (L1 && t == 32);

  for (int pass = 0; pass < 4; ++pass){
    __syncthreads();
    if (wn == pass){
      #pragma unroll
      for (int m = 0; m < 8; ++m){
        const int rowb = wm*128 + m*16 + (sl << 2);
        #pragma unroll
        for (int n = 0; n < 4; ++n){
          const int colb = n*16 + lr;
          const f32x4 v = acc[m][n];
          #pragma unroll
          for (int r = 0; r < 4; ++r)
            GLDS[(rowb + r)*GST + colb] = v[r];
        }
      }
    }
    __syncthreads();
    #pragma unroll
    for (int it = 0; it < 8; ++it){
      const int cid = it*512 + tid;
      const int row = cid >> 4;
      const int l   = cid & 15;
      const int rowg = r0 + row;
      const int hd   = (c0v >> 2) + pass*16 + l;
      float4 gv = *(const float4*)&GLDS[row*GST + 4*l];
      float gi = gv.x, gf = gv.y, gg = gv.z, go = gv.w;
      const int s  = rowg >> 3;
      const int bb = rowg & 7;
      const int pos = s - WWIN + t;
      if (!L1){
        const int p0r = (pos < 0 ? 0 : pos)*8 + bb;
        const ushort4 pv = *(const ushort4*)&P0[(size_t)p0r*GDIM + 4*hd];
        gi += bf2f(pv.x); gf += bf2f(pv.y); gg += bf2f(pv.z); go += bf2f(pv.w);
      } else {
        float4 bv = *(const float4*)&br1[4*hd];
        gi += bv.x; gf += bv.y; gg += bv.z; go += bv.w;
      }
      const size_t sidx = (size_t)rowg*HDIM + hd;
      float cp = cbuf[sidx];
      float i_ = sigm(gi), f_ = sigm(gf), g_ = tanh_f(gg), o_ = sigm(go);
      float cn = f_*cp + i_*g_;
      float hn = o_*tanh_f(cn);
      if (pos < 0){ cn = 0.f; hn = 0.f; }
      cbuf[sidx] = cn;
      if (finalStep) out[sidx] = hn;
      else           hw[sidx]  = f2bf(hn);
    }
  }
}

extern "C" void kernel_launch(void* const* d_in, const int* in_sizes, int n_in,
                              void* d_out, int out_size, void* d_ws, size_t ws_size,
                              hipStream_t stream)
{
  const int*   enc  = (const int*)d_in[0];
  const float* tbl  = (const float*)d_in[1];
  const float* wih0 = (const float*)d_in[2];
  const float* whh0 = (const float*)d_in[3];
  const float* bih0 = (const float*)d_in[4];
  const float* bhh0 = (const float*)d_in[5];
  const float* wih1 = (const float*)d_in[6];
  const float* whh1 = (const float*)d_in[7];
  const float* bih1 = (const float*)d_in[8];
  const float* bhh1 = (const float*)d_in[9];
  float* out = (float*)d_out;

  char* ws = (char*)d_ws;
  size_t off = 0;
  auto alloc = [&](size_t bytes){
    char* p = ws + off; off += (bytes + 255) & ~(size_t)255; return p;
  };
  unsigned short* E     = (unsigned short*)alloc((size_t)NROWS*512*2);
  unsigned short* BrIh0 = (unsigned short*)alloc((size_t)GDIM*512*2);
  unsigned short* Br0   = (unsigned short*)alloc((size_t)GDIM*512*2);
  unsigned short* Br1   = (unsigned short*)alloc((size_t)GDIM*1024*2);
  float* bias0r = (float*)alloc(GDIM*4);
  float* br1    = (float*)alloc(GDIM*4);
  unsigned short* P0 = (unsigned short*)alloc((size_t)NROWS*GDIM*2);
  unsigned short* h0 = (unsigned short*)alloc((size_t)2*NROWS*HDIM*2);
  unsigned short* h1 = (unsigned short*)alloc((size_t)2*NROWS*HDIM*2);
  float* c0 = (float*)alloc((size_t)NROWS*HDIM*4);   // fallback path only
  float* c1 = (float*)alloc((size_t)NROWS*HDIM*4);   // fallback path only
  unsigned* bar = (unsigned*)alloc(4096);            // 32 bands x 128B
  if (off > ws_size) return;  // workspace too small — would need fallback

  (void)hipFuncSetAttribute(reinterpret_cast<const void*>(persist_kernel),
                            hipFuncAttributeMaxDynamicSharedMemorySize, 65536);
  (void)hipFuncSetAttribute(reinterpret_cast<const void*>(step_kernel),
                            hipFuncAttributeMaxDynamicSharedMemorySize, 131072);

  // zero h0,h1,c0,c1,bar (contiguous: 8+8+8+8 MB + 4 KB)
  hipMemsetAsync(h0, 0, (size_t)33558528, stream);

  prep_weights<<<2048, 256, 0, stream>>>(wih0, whh0, bih0, bhh0,
                                         wih1, whh1, bih1, bhh1,
                                         BrIh0, Br0, Br1, bias0r, br1);
  gather_embed<<<4096, 256, 0, stream>>>(enc, tbl, E);
  p0_gemm<<<512, 256, 0, stream>>>(E, BrIh0, bias0r, P0);

  int occ = 0;
  hipError_t oe = hipOccupancyMaxActiveBlocksPerMultiprocessor(
      &occ, reinterpret_cast<const void*>(persist_kernel), 256, 49152);
  bool coop = (oe == hipSuccess && occ >= 2);
  if (coop){
    void* kargs[] = {&h0, &h1, &Br0, &Br1, &P0, &br1, &out, &bar};
    hipError_t le = hipLaunchCooperativeKernel(
        reinterpret_cast<const void*>(persist_kernel),
        dim3(512), dim3(256), kargs, 49152, stream);
    if (le != hipSuccess) coop = false;
  }
  if (!coop){
    for (int tau = 0; tau <= 33; ++tau){
      const int grid = (tau == 0 || tau == 33) ? 128 : 256;
      const int boff = (tau == 33) ? 128 : 0;
      step_kernel<<<grid, 512, 131072, stream>>>(h0, h1, c0, c1, Br0, Br1,
                                                 P0, br1, out, tau, boff);
    }
  }
}